// Round 2
// baseline (442.127 us; speedup 1.0000x reference)
//
#include <hip/hip_runtime.h>
#include <hip/hip_bf16.h>
#include <math.h>

// bf16 MFMA fragment types
typedef __attribute__((ext_vector_type(8))) short bfrag;
typedef __attribute__((ext_vector_type(4))) float f32x4;
typedef __attribute__((ext_vector_type(4))) short short4v;

#define LDK 136  // padded LDS row length in bf16 elems

// ---------------------------------------------------------------------------
// Prep: W[128][128] fp32 -> bf16 transposed WT[n][k], via LDS tile so both
// global reads (float4) and global writes (bfrag 16B) are coalesced.
// Order in ws: 0=Wq 1=Wk 2=Wv 3=Wo 4=W1 5=W2 6=Wq_s 7=Wk_s
// ---------------------------------------------------------------------------
__global__ __launch_bounds__(256) void prep_weights(
    const float* __restrict__ Wq, const float* __restrict__ Wk,
    const float* __restrict__ Wv, const float* __restrict__ Wo,
    const float* __restrict__ W1, const float* __restrict__ W2,
    const float* __restrict__ Wqs, const float* __restrict__ Wks,
    __hip_bfloat16* __restrict__ out)
{
    __shared__ __align__(16) __hip_bfloat16 t[128 * 129];
    const float* Ws[8] = {Wq, Wk, Wv, Wo, W1, W2, Wqs, Wks};
    const float* W = Ws[blockIdx.x];
    __hip_bfloat16* o = out + (size_t)blockIdx.x * 16384;
#pragma unroll
    for (int p = 0; p < 16; ++p) {
        int v = p * 256 + threadIdx.x;          // float4 index, 4096 total
        float4 f = ((const float4*)W)[v];
        int flat = v * 4;
        __hip_bfloat16* d = t + (flat >> 7) * 129 + (flat & 127);
        d[0] = __float2bfloat16(f.x); d[1] = __float2bfloat16(f.y);
        d[2] = __float2bfloat16(f.z); d[3] = __float2bfloat16(f.w);
    }
    __syncthreads();
#pragma unroll
    for (int p = 0; p < 8; ++p) {
        int i = p * 256 + threadIdx.x;          // 8-elem group index, 2048 total
        int n = i >> 4, k0 = (i & 15) * 8;
        __hip_bfloat16 v[8];
#pragma unroll
        for (int j = 0; j < 8; ++j) v[j] = t[(k0 + j) * 129 + n];  // WT[n][k]=W[k][n]
        *(bfrag*)(o + n * 128 + k0) = *(const bfrag*)v;
    }
}

// wave computes row-tiles {0,1} x col-tiles {2w,2w+1} of OUT[32][128] = A[32][128] @ W
__device__ __forceinline__ void mm_acc(const __hip_bfloat16* A,
                                       const __hip_bfloat16* __restrict__ wT,
                                       int m, int quad, int ct0, f32x4 acc[2][2])
{
    const f32x4 z = {0.f, 0.f, 0.f, 0.f};
    acc[0][0] = z; acc[0][1] = z; acc[1][0] = z; acc[1][1] = z;
#pragma unroll
    for (int kk = 0; kk < 128; kk += 32) {
        const int k = kk + quad * 8;
        bfrag a0 = *(const bfrag*)(A + m * LDK + k);
        bfrag a1 = *(const bfrag*)(A + (16 + m) * LDK + k);
        bfrag b0 = *(const bfrag*)(wT + (size_t)(ct0 * 16 + m) * 128 + k);
        bfrag b1 = *(const bfrag*)(wT + (size_t)((ct0 + 1) * 16 + m) * 128 + k);
        acc[0][0] = __builtin_amdgcn_mfma_f32_16x16x32_bf16(a0, b0, acc[0][0], 0, 0, 0);
        acc[1][0] = __builtin_amdgcn_mfma_f32_16x16x32_bf16(a1, b0, acc[1][0], 0, 0, 0);
        acc[0][1] = __builtin_amdgcn_mfma_f32_16x16x32_bf16(a0, b1, acc[0][1], 0, 0, 0);
        acc[1][1] = __builtin_amdgcn_mfma_f32_16x16x32_bf16(a1, b1, acc[1][1], 0, 0, 0);
    }
}

// LayerNorm over 128 elems x 32 rows: 8 threads/row, 16 elems each
__device__ __forceinline__ void ln_step(const __hip_bfloat16* in, __hip_bfloat16* outb,
                                        const float* __restrict__ g,
                                        const float* __restrict__ bb, int tid)
{
    int row = tid >> 3;
    int part = tid & 7;
    const __hip_bfloat16* p = in + row * LDK + part * 16;
    float x[16];
#pragma unroll
    for (int j = 0; j < 16; ++j) x[j] = __bfloat162float(p[j]);
    float s = 0.f, s2 = 0.f;
#pragma unroll
    for (int j = 0; j < 16; ++j) { s += x[j]; s2 += x[j] * x[j]; }
#pragma unroll
    for (int off = 1; off < 8; off <<= 1) {
        s += __shfl_xor(s, off, 64);
        s2 += __shfl_xor(s2, off, 64);
    }
    float mu = s * (1.f / 128.f);
    float var = s2 * (1.f / 128.f) - mu * mu;
    float sc = rsqrtf(var + 1e-5f);
    __hip_bfloat16* o = outb + row * LDK + part * 16;
#pragma unroll
    for (int j = 0; j < 16; ++j) {
        int c = part * 16 + j;
        o[j] = __float2bfloat16((x[j] - mu) * sc * g[c] + bb[c]);
    }
}

__global__ __launch_bounds__(256) void fused_model(
    const float* __restrict__ agent_embed,   // [B,16,128]
    const float* __restrict__ city_embed,    // [B,128,128]
    const int* __restrict__ acts,            // [B,16]
    const __hip_bfloat16* __restrict__ wts,  // 8 x WT[128][128] bf16
    const float* __restrict__ ln1g, const float* __restrict__ ln1b,
    const float* __restrict__ b1, const float* __restrict__ b2,
    const float* __restrict__ ln2g, const float* __restrict__ ln2b,
    float* __restrict__ out)                 // [B,16,16]
{
    __shared__ __align__(16) __hip_bfloat16 sXA[32 * LDK];  // agent -> O -> Z
    __shared__ __align__(16) __hip_bfloat16 sXS[32 * LDK];  // selected -> CAC
    __shared__ __align__(16) __hip_bfloat16 sK [32 * LDK];  // K -> H -> QS
    __shared__ __align__(16) __hip_bfloat16 sV [32 * LDK];  // Vt[2][8][16][16] -> F1
    __shared__ __align__(16) __hip_bfloat16 sKS[32 * LDK];  // KS (live to end)
    __shared__ __align__(16) __hip_bfloat16 sQ [32 * LDK];  // Q (P tiles) -> Y
    __shared__ __align__(16) __hip_bfloat16 sZero[8];       // zero K-pad stub
    __shared__ int sActs[32];

    const int tid = threadIdx.x;
    const int lane = tid & 63;
    const int wave = tid >> 6;
    const int m = lane & 15;
    const int quad = lane >> 4;
    const int ct0 = wave * 2;
    const int b0 = blockIdx.x * 2;

    // ---------------- stage A: acts, zero stub, XA (agent), XS (gathered city)
    if (tid < 32) sActs[tid] = acts[b0 * 16 + tid];
    if (tid < 8) sZero[tid] = __float2bfloat16(0.f);
    {
        const float4* src = (const float4*)(agent_embed + (size_t)b0 * 16 * 128);
#pragma unroll
        for (int p = 0; p < 4; ++p) {
            int v = p * 256 + tid;
            float4 f = src[v];
            int flat = v * 4;
            __hip_bfloat16* d = sXA + (flat >> 7) * LDK + (flat & 127);
            d[0] = __float2bfloat16(f.x); d[1] = __float2bfloat16(f.y);
            d[2] = __float2bfloat16(f.z); d[3] = __float2bfloat16(f.w);
        }
    }
    {
        int r = tid >> 3, part = tid & 7;
        int b = b0 + (r >> 4), i = r & 15;
        int act = acts[b * 16 + i];
        const float4* src = (const float4*)(city_embed + ((size_t)b * 128 + act) * 128);
        __hip_bfloat16* d = sXS + r * LDK + part * 16;
#pragma unroll
        for (int p = 0; p < 4; ++p) {
            float4 f = src[part * 4 + p];
            d[p * 4 + 0] = __float2bfloat16(f.x); d[p * 4 + 1] = __float2bfloat16(f.y);
            d[p * 4 + 2] = __float2bfloat16(f.z); d[p * 4 + 3] = __float2bfloat16(f.w);
        }
    }
    __syncthreads();

    f32x4 acc[2][2];
#define STORE_PLAIN(dst)                                                        \
    for (int rt = 0; rt < 2; ++rt)                                              \
        for (int c = 0; c < 2; ++c)                                             \
            for (int r = 0; r < 4; ++r)                                         \
                dst[(rt * 16 + quad * 4 + r) * LDK + (ct0 + c) * 16 + m] =      \
                    __float2bfloat16(acc[rt][c][r]);

    // ---------------- S1: K = agent @ Wk
    mm_acc(sXA, wts + 1 * 16384, m, quad, ct0, acc); STORE_PLAIN(sK);
    // ---------------- S2: V = agent @ Wv, stored TRANSPOSED: Vt[g][h][d][k]
    mm_acc(sXA, wts + 2 * 16384, m, quad, ct0, acc);
#pragma unroll
    for (int rt = 0; rt < 2; ++rt)
#pragma unroll
        for (int c = 0; c < 2; ++c) {
            __hip_bfloat16 pk[4];
#pragma unroll
            for (int r = 0; r < 4; ++r) pk[r] = __float2bfloat16(acc[rt][c][r]);
            // Vt[g=rt][h=ct0+c][d=m][k=quad*4+r]
            *(short4v*)(sV + ((rt * 8 + ct0 + c) * 16 + m) * 16 + quad * 4) =
                *(const short4v*)pk;
        }
    // ---------------- S3: KS = agent @ Wk_s
    mm_acc(sXA, wts + 7 * 16384, m, quad, ct0, acc); STORE_PLAIN(sKS);
    // ---------------- S4: Q = selected @ Wq
    mm_acc(sXS, wts + 0 * 16384, m, quad, ct0, acc); STORE_PLAIN(sQ);
    __syncthreads();

    // ---------------- S5: masked 8-head attention via MFMA (K padded 16->32).
    // Wave handles 4 (g,h) pairs; all tiles it touches are wave-private.
    {
        const f32x4 z4 = {0.f, 0.f, 0.f, 0.f};
#pragma unroll
        for (int pp = 0; pp < 4; ++pp) {
            const int p = wave * 4 + pp;
            const int g = p >> 3, h = p & 7;
            // S = Q_h @ K_h^T : A = Q rows, B = K rows (X·Y^T trick)
            const __hip_bfloat16* qa = (quad < 2)
                ? sQ + (g * 16 + m) * LDK + h * 16 + quad * 8 : sZero;
            const __hip_bfloat16* kb = (quad < 2)
                ? sK + (g * 16 + m) * LDK + h * 16 + quad * 8 : sZero;
            f32x4 sc = __builtin_amdgcn_mfma_f32_16x16x32_bf16(
                *(const bfrag*)qa, *(const bfrag*)kb, z4, 0, 0, 0);
            // sc[r] = S[q=quad*4+r][k=m] (pre-scale)
            const int ak = sActs[g * 16 + m];
#pragma unroll
            for (int r = 0; r < 4; ++r) {
                int q = quad * 4 + r;
                int aqv = sActs[g * 16 + q];
                bool keep = (aqv == 0) ? (q == m) : (aqv == ak);
                // scores tiny (|s|<~1): softmax without max-sub is exact enough
                float e = keep ? __expf(sc[r] * 0.25f) : 0.f;
                float s = e;
                s += __shfl_xor(s, 1, 16);
                s += __shfl_xor(s, 2, 16);
                s += __shfl_xor(s, 4, 16);
                s += __shfl_xor(s, 8, 16);
                // P (normalized) into our own Q tile (dead after this stage)
                sQ[(g * 16 + q) * LDK + h * 16 + m] = __float2bfloat16(__fdividef(e, s));
            }
            // O = P @ V_h : A = P rows, B[k][d] = Vt[g][h][d][k] rows
            const __hip_bfloat16* pa = (quad < 2)
                ? sQ + (g * 16 + m) * LDK + h * 16 + quad * 8 : sZero;
            const __hip_bfloat16* vb = (quad < 2)
                ? sV + ((g * 8 + h) * 16 + m) * 16 + quad * 8 : sZero;
            f32x4 o4 = __builtin_amdgcn_mfma_f32_16x16x32_bf16(
                *(const bfrag*)pa, *(const bfrag*)vb, z4, 0, 0, 0);
#pragma unroll
            for (int r = 0; r < 4; ++r)
                sXA[(g * 16 + quad * 4 + r) * LDK + h * 16 + m] =
                    __float2bfloat16(o4[r]);
        }
    }
    __syncthreads();

    // ---------------- S6: Y = O @ Wo + selected (into sQ)
    mm_acc(sXA, wts + 3 * 16384, m, quad, ct0, acc);
#pragma unroll
    for (int rt = 0; rt < 2; ++rt)
#pragma unroll
        for (int c = 0; c < 2; ++c)
#pragma unroll
            for (int r = 0; r < 4; ++r) {
                int row = rt * 16 + quad * 4 + r, col = (ct0 + c) * 16 + m;
                float v = acc[rt][c][r] + __bfloat162float(sXS[row * LDK + col]);
                sQ[row * LDK + col] = __float2bfloat16(v);
            }
    __syncthreads();

    // ---------------- S7: LN1(Y) -> H (into sK)
    ln_step(sQ, sK, ln1g, ln1b, tid);
    __syncthreads();

    // ---------------- S8: F1 = relu(H @ W1 + b1) (into sV; Vt is dead)
    mm_acc(sK, wts + 4 * 16384, m, quad, ct0, acc);
#pragma unroll
    for (int rt = 0; rt < 2; ++rt)
#pragma unroll
        for (int c = 0; c < 2; ++c) {
            int col = (ct0 + c) * 16 + m;
            float bias = b1[col];
#pragma unroll
            for (int r = 0; r < 4; ++r) {
                int row = rt * 16 + quad * 4 + r;
                sV[row * LDK + col] = __float2bfloat16(fmaxf(acc[rt][c][r] + bias, 0.f));
            }
        }
    __syncthreads();

    // ---------------- S9: Z = H + F1 @ W2 + b2 (into sXA)
    mm_acc(sV, wts + 5 * 16384, m, quad, ct0, acc);
#pragma unroll
    for (int rt = 0; rt < 2; ++rt)
#pragma unroll
        for (int c = 0; c < 2; ++c) {
            int col = (ct0 + c) * 16 + m;
            float bias = b2[col];
#pragma unroll
            for (int r = 0; r < 4; ++r) {
                int row = rt * 16 + quad * 4 + r;
                float v = acc[rt][c][r] + bias + __bfloat162float(sK[row * LDK + col]);
                sXA[row * LDK + col] = __float2bfloat16(v);
            }
        }
    __syncthreads();

    // ---------------- S10: LN2(Z) -> CAC (into sXS)
    ln_step(sXA, sXS, ln2g, ln2b, tid);
    __syncthreads();

    // ---------------- S11: QS = CAC @ Wq_s (into sK)
    mm_acc(sXS, wts + 6 * 16384, m, quad, ct0, acc);
    STORE_PLAIN(sK);
    __syncthreads();

    // ---------------- S12: logits = clip*tanh(QS @ KS^T / sqrt(E)), mask, store
    if (wave < 2) {
        int g = wave;
        f32x4 la = {0.f, 0.f, 0.f, 0.f};
#pragma unroll
        for (int kk = 0; kk < 128; kk += 32) {
            int k = kk + quad * 8;
            bfrag a = *(const bfrag*)(sK + (g * 16 + m) * LDK + k);   // QS rows
            bfrag b = *(const bfrag*)(sKS + (g * 16 + m) * LDK + k);  // KS rows
            la = __builtin_amdgcn_mfma_f32_16x16x32_bf16(a, b, la, 0, 0, 0);
        }
        int b = b0 + g;
        int kcol = m;
        int ak = sActs[g * 16 + kcol];
#pragma unroll
        for (int r = 0; r < 4; ++r) {
            int q = quad * 4 + r;
            int aq = sActs[g * 16 + q];
            float v = la[r] * 0.0883883476483184f;  // 1/sqrt(128)
            v = 10.f * tanhf(v);
            bool conflict = (aq == 0) ? (q == kcol) : (aq == ak);
            out[((size_t)b * 16 + q) * 16 + kcol] = conflict ? v : -1e9f;
        }
    }
#undef STORE_PLAIN
}

extern "C" void kernel_launch(void* const* d_in, const int* in_sizes, int n_in,
                              void* d_out, int out_size, void* d_ws, size_t ws_size,
                              hipStream_t stream)
{
    const float* agent = (const float*)d_in[0];
    const float* city  = (const float*)d_in[1];
    const int*   acts  = (const int*)d_in[2];
    const float* Wq  = (const float*)d_in[3];
    const float* Wk  = (const float*)d_in[4];
    const float* Wv  = (const float*)d_in[5];
    const float* Wo  = (const float*)d_in[6];
    const float* l1g = (const float*)d_in[7];
    const float* l1b = (const float*)d_in[8];
    const float* W1  = (const float*)d_in[9];
    const float* b1  = (const float*)d_in[10];
    const float* W2  = (const float*)d_in[11];
    const float* b2  = (const float*)d_in[12];
    const float* l2g = (const float*)d_in[13];
    const float* l2b = (const float*)d_in[14];
    const float* Wqs = (const float*)d_in[15];
    const float* Wks = (const float*)d_in[16];
    float* out = (float*)d_out;

    int B = in_sizes[2] / 16;  // acts is [B,16]
    __hip_bfloat16* wts = (__hip_bfloat16*)d_ws;  // 8*16384 bf16 = 256 KB

    prep_weights<<<8, 256, 0, stream>>>(Wq, Wk, Wv, Wo, W1, W2, Wqs, Wks, wts);
    fused_model<<<B / 2, 256, 0, stream>>>(agent, city, acts, wts, l1g, l1b,
                                           b1, b2, l2g, l2b, out);
}

// Round 3
// 434.939 us; speedup vs baseline: 1.0165x; 1.0165x over previous
//
#include <hip/hip_runtime.h>
#include <hip/hip_bf16.h>
#include <math.h>

// bf16 MFMA fragment types
typedef __attribute__((ext_vector_type(8))) short bfrag;
typedef __attribute__((ext_vector_type(4))) float f32x4;
typedef __attribute__((ext_vector_type(4))) short short4v;

#define LDK 136  // padded LDS row length in bf16 elems

// ---------------------------------------------------------------------------
// Prep: W[128][128] fp32 -> bf16 transposed WT[n][k].
// 64 blocks: (matrix 0..7) x (16-row output slab 0..7). Small LDS tile so
// global reads are coalesced float4 and global writes are coalesced 16B bf16.
// Order in ws: 0=Wq 1=Wk 2=Wv 3=Wo 4=W1 5=W2 6=Wq_s 7=Wk_s
// ---------------------------------------------------------------------------
__global__ __launch_bounds__(256) void prep_weights(
    const float* __restrict__ Wq, const float* __restrict__ Wk,
    const float* __restrict__ Wv, const float* __restrict__ Wo,
    const float* __restrict__ W1, const float* __restrict__ W2,
    const float* __restrict__ Wqs, const float* __restrict__ Wks,
    __hip_bfloat16* __restrict__ out)
{
    __shared__ __hip_bfloat16 t[128 * 17];  // t[k][n'] for n' in slab, +1 pad
    const float* Ws[8] = {Wq, Wk, Wv, Wo, W1, W2, Wqs, Wks};
    const int mat = blockIdx.x >> 3;
    const int slab = blockIdx.x & 7;
    const float* W = Ws[mat];
    const int n0 = slab * 16;
    __hip_bfloat16* o = out + (size_t)mat * 16384 + (size_t)n0 * 128;

#pragma unroll
    for (int p = 0; p < 2; ++p) {
        int idx = p * 256 + threadIdx.x;  // 512 float4 slots = 128 rows x 4
        int k = idx >> 2, c4 = idx & 3;
        float4 f = *(const float4*)(W + k * 128 + n0 + c4 * 4);
        __hip_bfloat16* d = t + k * 17 + c4 * 4;
        d[0] = __float2bfloat16(f.x); d[1] = __float2bfloat16(f.y);
        d[2] = __float2bfloat16(f.z); d[3] = __float2bfloat16(f.w);
    }
    __syncthreads();
    {
        int n = threadIdx.x >> 4;          // 0..15 within slab
        int k0 = (threadIdx.x & 15) * 8;   // 0..120
        __hip_bfloat16 v[8];
#pragma unroll
        for (int j = 0; j < 8; ++j) v[j] = t[(k0 + j) * 17 + n];  // WT[n][k]=W[k][n]
        *(bfrag*)(o + n * 128 + k0) = *(const bfrag*)v;
    }
}

// wave computes row-tiles {0,1} x col-tiles {2w,2w+1} of OUT[32][128] = A[32][128] @ W
__device__ __forceinline__ void mm_acc(const __hip_bfloat16* A,
                                       const __hip_bfloat16* __restrict__ wT,
                                       int m, int quad, int ct0, f32x4 acc[2][2])
{
    const f32x4 z = {0.f, 0.f, 0.f, 0.f};
    acc[0][0] = z; acc[0][1] = z; acc[1][0] = z; acc[1][1] = z;
#pragma unroll
    for (int kk = 0; kk < 128; kk += 32) {
        const int k = kk + quad * 8;
        bfrag a0 = *(const bfrag*)(A + m * LDK + k);
        bfrag a1 = *(const bfrag*)(A + (16 + m) * LDK + k);
        bfrag b0 = *(const bfrag*)(wT + (size_t)(ct0 * 16 + m) * 128 + k);
        bfrag b1 = *(const bfrag*)(wT + (size_t)((ct0 + 1) * 16 + m) * 128 + k);
        acc[0][0] = __builtin_amdgcn_mfma_f32_16x16x32_bf16(a0, b0, acc[0][0], 0, 0, 0);
        acc[1][0] = __builtin_amdgcn_mfma_f32_16x16x32_bf16(a1, b0, acc[1][0], 0, 0, 0);
        acc[0][1] = __builtin_amdgcn_mfma_f32_16x16x32_bf16(a0, b1, acc[0][1], 0, 0, 0);
        acc[1][1] = __builtin_amdgcn_mfma_f32_16x16x32_bf16(a1, b1, acc[1][1], 0, 0, 0);
    }
}

// LayerNorm over 128 elems x 32 rows: 8 threads/row, 16 elems each
__device__ __forceinline__ void ln_step(const __hip_bfloat16* in, __hip_bfloat16* outb,
                                        const float* __restrict__ g,
                                        const float* __restrict__ bb, int tid)
{
    int row = tid >> 3;
    int part = tid & 7;
    const __hip_bfloat16* p = in + row * LDK + part * 16;
    float x[16];
#pragma unroll
    for (int j = 0; j < 16; ++j) x[j] = __bfloat162float(p[j]);
    float s = 0.f, s2 = 0.f;
#pragma unroll
    for (int j = 0; j < 16; ++j) { s += x[j]; s2 += x[j] * x[j]; }
#pragma unroll
    for (int off = 1; off < 8; off <<= 1) {
        s += __shfl_xor(s, off, 64);
        s2 += __shfl_xor(s2, off, 64);
    }
    float mu = s * (1.f / 128.f);
    float var = s2 * (1.f / 128.f) - mu * mu;
    float sc = rsqrtf(var + 1e-5f);
    __hip_bfloat16* o = outb + row * LDK + part * 16;
#pragma unroll
    for (int j = 0; j < 16; ++j) {
        int c = part * 16 + j;
        o[j] = __float2bfloat16((x[j] - mu) * sc * g[c] + bb[c]);
    }
}

__global__ __launch_bounds__(256) void fused_model(
    const float* __restrict__ agent_embed,   // [B,16,128]
    const float* __restrict__ city_embed,    // [B,128,128]
    const int* __restrict__ acts,            // [B,16]
    const __hip_bfloat16* __restrict__ wts,  // 8 x WT[128][128] bf16
    const float* __restrict__ ln1g, const float* __restrict__ ln1b,
    const float* __restrict__ b1, const float* __restrict__ b2,
    const float* __restrict__ ln2g, const float* __restrict__ ln2b,
    float* __restrict__ out)                 // [B,16,16]
{
    __shared__ __align__(16) __hip_bfloat16 sXA[32 * LDK];  // agent -> O -> Z
    __shared__ __align__(16) __hip_bfloat16 sXS[32 * LDK];  // selected -> CAC
    __shared__ __align__(16) __hip_bfloat16 sK [32 * LDK];  // K -> H -> QS
    __shared__ __align__(16) __hip_bfloat16 sV [32 * LDK];  // Vt[2][8][16][16] -> F1
    __shared__ __align__(16) __hip_bfloat16 sKS[32 * LDK];  // KS (live to end)
    __shared__ __align__(16) __hip_bfloat16 sQ [32 * LDK];  // Q (P tiles) -> Y
    __shared__ __align__(16) __hip_bfloat16 sZero[8];       // zero K-pad stub
    __shared__ int sActs[32];

    const int tid = threadIdx.x;
    const int lane = tid & 63;
    const int wave = tid >> 6;
    const int m = lane & 15;
    const int quad = lane >> 4;
    const int ct0 = wave * 2;
    const int b0 = blockIdx.x * 2;

    // ---------------- stage A: acts, zero stub, XA (agent), XS (gathered city)
    if (tid < 32) sActs[tid] = acts[b0 * 16 + tid];
    if (tid < 8) sZero[tid] = __float2bfloat16(0.f);
    {
        const float4* src = (const float4*)(agent_embed + (size_t)b0 * 16 * 128);
#pragma unroll
        for (int p = 0; p < 4; ++p) {
            int v = p * 256 + tid;
            float4 f = src[v];
            int flat = v * 4;
            __hip_bfloat16* d = sXA + (flat >> 7) * LDK + (flat & 127);
            d[0] = __float2bfloat16(f.x); d[1] = __float2bfloat16(f.y);
            d[2] = __float2bfloat16(f.z); d[3] = __float2bfloat16(f.w);
        }
    }
    {
        int r = tid >> 3, part = tid & 7;
        int b = b0 + (r >> 4), i = r & 15;
        int act = acts[b * 16 + i];
        const float4* src = (const float4*)(city_embed + ((size_t)b * 128 + act) * 128);
        __hip_bfloat16* d = sXS + r * LDK + part * 16;
#pragma unroll
        for (int p = 0; p < 4; ++p) {
            float4 f = src[part * 4 + p];
            d[p * 4 + 0] = __float2bfloat16(f.x); d[p * 4 + 1] = __float2bfloat16(f.y);
            d[p * 4 + 2] = __float2bfloat16(f.z); d[p * 4 + 3] = __float2bfloat16(f.w);
        }
    }
    __syncthreads();

    f32x4 acc[2][2];
#define STORE_PLAIN(dst)                                                        \
    for (int rt = 0; rt < 2; ++rt)                                              \
        for (int c = 0; c < 2; ++c)                                             \
            for (int r = 0; r < 4; ++r)                                         \
                dst[(rt * 16 + quad * 4 + r) * LDK + (ct0 + c) * 16 + m] =      \
                    __float2bfloat16(acc[rt][c][r]);

    // ---------------- S1: K = agent @ Wk
    mm_acc(sXA, wts + 1 * 16384, m, quad, ct0, acc); STORE_PLAIN(sK);
    // ---------------- S2: V = agent @ Wv, stored TRANSPOSED: Vt[g][h][d][k]
    mm_acc(sXA, wts + 2 * 16384, m, quad, ct0, acc);
#pragma unroll
    for (int rt = 0; rt < 2; ++rt)
#pragma unroll
        for (int c = 0; c < 2; ++c) {
            __hip_bfloat16 pk[4];
#pragma unroll
            for (int r = 0; r < 4; ++r) pk[r] = __float2bfloat16(acc[rt][c][r]);
            // Vt[g=rt][h=ct0+c][d=m][k=quad*4+r]
            *(short4v*)(sV + ((rt * 8 + ct0 + c) * 16 + m) * 16 + quad * 4) =
                *(const short4v*)pk;
        }
    // ---------------- S3: KS = agent @ Wk_s
    mm_acc(sXA, wts + 7 * 16384, m, quad, ct0, acc); STORE_PLAIN(sKS);
    // ---------------- S4: Q = selected @ Wq
    mm_acc(sXS, wts + 0 * 16384, m, quad, ct0, acc); STORE_PLAIN(sQ);
    __syncthreads();

    // ---------------- S5: masked 8-head attention via MFMA (K padded 16->32).
    {
        const f32x4 z4 = {0.f, 0.f, 0.f, 0.f};
#pragma unroll
        for (int pp = 0; pp < 4; ++pp) {
            const int p = wave * 4 + pp;
            const int g = p >> 3, h = p & 7;
            // S = Q_h @ K_h^T : A = Q rows, B = K rows (X·Y^T trick)
            const __hip_bfloat16* qa = (quad < 2)
                ? sQ + (g * 16 + m) * LDK + h * 16 + quad * 8 : sZero;
            const __hip_bfloat16* kb = (quad < 2)
                ? sK + (g * 16 + m) * LDK + h * 16 + quad * 8 : sZero;
            f32x4 sc = __builtin_amdgcn_mfma_f32_16x16x32_bf16(
                *(const bfrag*)qa, *(const bfrag*)kb, z4, 0, 0, 0);
            // sc[r] = S[q=quad*4+r][k=m] (pre-scale)
            const int ak = sActs[g * 16 + m];
#pragma unroll
            for (int r = 0; r < 4; ++r) {
                int q = quad * 4 + r;
                int aqv = sActs[g * 16 + q];
                bool keep = (aqv == 0) ? (q == m) : (aqv == ak);
                // scores tiny (|s|<~1): softmax without max-sub is exact enough
                float e = keep ? __expf(sc[r] * 0.25f) : 0.f;
                float s = e;
                s += __shfl_xor(s, 1, 16);
                s += __shfl_xor(s, 2, 16);
                s += __shfl_xor(s, 4, 16);
                s += __shfl_xor(s, 8, 16);
                sQ[(g * 16 + q) * LDK + h * 16 + m] = __float2bfloat16(__fdividef(e, s));
            }
            // O = P @ V_h : A = P rows, B[k][d] = Vt[g][h][d][k] rows
            const __hip_bfloat16* pa = (quad < 2)
                ? sQ + (g * 16 + m) * LDK + h * 16 + quad * 8 : sZero;
            const __hip_bfloat16* vb = (quad < 2)
                ? sV + ((g * 8 + h) * 16 + m) * 16 + quad * 8 : sZero;
            f32x4 o4 = __builtin_amdgcn_mfma_f32_16x16x32_bf16(
                *(const bfrag*)pa, *(const bfrag*)vb, z4, 0, 0, 0);
#pragma unroll
            for (int r = 0; r < 4; ++r)
                sXA[(g * 16 + quad * 4 + r) * LDK + h * 16 + m] =
                    __float2bfloat16(o4[r]);
        }
    }
    __syncthreads();

    // ---------------- S6: Y = O @ Wo + selected (into sQ)
    mm_acc(sXA, wts + 3 * 16384, m, quad, ct0, acc);
#pragma unroll
    for (int rt = 0; rt < 2; ++rt)
#pragma unroll
        for (int c = 0; c < 2; ++c)
#pragma unroll
            for (int r = 0; r < 4; ++r) {
                int row = rt * 16 + quad * 4 + r, col = (ct0 + c) * 16 + m;
                float v = acc[rt][c][r] + __bfloat162float(sXS[row * LDK + col]);
                sQ[row * LDK + col] = __float2bfloat16(v);
            }
    __syncthreads();

    // ---------------- S7: LN1(Y) -> H (into sK)
    ln_step(sQ, sK, ln1g, ln1b, tid);
    __syncthreads();

    // ---------------- S8: F1 = relu(H @ W1 + b1) (into sV; Vt is dead)
    mm_acc(sK, wts + 4 * 16384, m, quad, ct0, acc);
#pragma unroll
    for (int rt = 0; rt < 2; ++rt)
#pragma unroll
        for (int c = 0; c < 2; ++c) {
            int col = (ct0 + c) * 16 + m;
            float bias = b1[col];
#pragma unroll
            for (int r = 0; r < 4; ++r) {
                int row = rt * 16 + quad * 4 + r;
                sV[row * LDK + col] = __float2bfloat16(fmaxf(acc[rt][c][r] + bias, 0.f));
            }
        }
    __syncthreads();

    // ---------------- S9: Z = H + F1 @ W2 + b2 (into sXA)
    mm_acc(sV, wts + 5 * 16384, m, quad, ct0, acc);
#pragma unroll
    for (int rt = 0; rt < 2; ++rt)
#pragma unroll
        for (int c = 0; c < 2; ++c) {
            int col = (ct0 + c) * 16 + m;
            float bias = b2[col];
#pragma unroll
            for (int r = 0; r < 4; ++r) {
                int row = rt * 16 + quad * 4 + r;
                float v = acc[rt][c][r] + bias + __bfloat162float(sK[row * LDK + col]);
                sXA[row * LDK + col] = __float2bfloat16(v);
            }
        }
    __syncthreads();

    // ---------------- S10: LN2(Z) -> CAC (into sXS)
    ln_step(sXA, sXS, ln2g, ln2b, tid);
    __syncthreads();

    // ---------------- S11: QS = CAC @ Wq_s (into sK)
    mm_acc(sXS, wts + 6 * 16384, m, quad, ct0, acc);
    STORE_PLAIN(sK);
    __syncthreads();

    // ---------------- S12: logits = clip*tanh(QS @ KS^T / sqrt(E)), mask, store
    if (wave < 2) {
        int g = wave;
        f32x4 la = {0.f, 0.f, 0.f, 0.f};
#pragma unroll
        for (int kk = 0; kk < 128; kk += 32) {
            int k = kk + quad * 8;
            bfrag a = *(const bfrag*)(sK + (g * 16 + m) * LDK + k);   // QS rows
            bfrag b = *(const bfrag*)(sKS + (g * 16 + m) * LDK + k);  // KS rows
            la = __builtin_amdgcn_mfma_f32_16x16x32_bf16(a, b, la, 0, 0, 0);
        }
        int b = b0 + g;
        int kcol = m;
        int ak = sActs[g * 16 + kcol];
#pragma unroll
        for (int r = 0; r < 4; ++r) {
            int q = quad * 4 + r;
            int aq = sActs[g * 16 + q];
            float v = la[r] * 0.0883883476483184f;  // 1/sqrt(128)
            v = 10.f * tanhf(v);
            bool conflict = (aq == 0) ? (q == kcol) : (aq == ak);
            out[((size_t)b * 16 + q) * 16 + kcol] = conflict ? v : -1e9f;
        }
    }
#undef STORE_PLAIN
}

extern "C" void kernel_launch(void* const* d_in, const int* in_sizes, int n_in,
                              void* d_out, int out_size, void* d_ws, size_t ws_size,
                              hipStream_t stream)
{
    const float* agent = (const float*)d_in[0];
    const float* city  = (const float*)d_in[1];
    const int*   acts  = (const int*)d_in[2];
    const float* Wq  = (const float*)d_in[3];
    const float* Wk  = (const float*)d_in[4];
    const float* Wv  = (const float*)d_in[5];
    const float* Wo  = (const float*)d_in[6];
    const float* l1g = (const float*)d_in[7];
    const float* l1b = (const float*)d_in[8];
    const float* W1  = (const float*)d_in[9];
    const float* b1  = (const float*)d_in[10];
    const float* W2  = (const float*)d_in[11];
    const float* b2  = (const float*)d_in[12];
    const float* l2g = (const float*)d_in[13];
    const float* l2b = (const float*)d_in[14];
    const float* Wqs = (const float*)d_in[15];
    const float* Wks = (const float*)d_in[16];
    float* out = (float*)d_out;

    int B = in_sizes[2] / 16;  // acts is [B,16]
    __hip_bfloat16* wts = (__hip_bfloat16*)d_ws;  // 8*16384 bf16 = 256 KB

    prep_weights<<<64, 256, 0, stream>>>(Wq, Wk, Wv, Wo, W1, W2, Wqs, Wks, wts);
    fused_model<<<B / 2, 256, 0, stream>>>(agent, city, acts, wts, l1g, l1b,
                                           b1, b2, l2g, l2b, out);
}